// Round 1
// baseline (212.350 us; speedup 1.0000x reference)
//
#include <hip/hip_runtime.h>

// Masked sum reduction: s = sum(items[i] for items[i] % 2 == 0), N = 2^25 fp32.
// Memory-bound: 128 MB read -> ~20 us floor at 6.3 TB/s.

__global__ void zero_out_kernel(float* out) {
    out[0] = 0.0f;
}

__global__ __launch_bounds__(256) void masked_sum_kernel(
        const float* __restrict__ in, float* __restrict__ out, int n4) {
    const float4* __restrict__ in4 = (const float4*)in;

    float s = 0.0f;
    int idx = blockIdx.x * blockDim.x + threadIdx.x;
    int stride = gridDim.x * blockDim.x;

    for (int i = idx; i < n4; i += stride) {
        float4 v = in4[i];
        // Inputs are integer-valued floats < 2^24, so int-cast is exact.
        if ((((int)v.x) & 1) == 0) s += v.x;
        if ((((int)v.y) & 1) == 0) s += v.y;
        if ((((int)v.z) & 1) == 0) s += v.z;
        if ((((int)v.w) & 1) == 0) s += v.w;
    }

    // Wave-level reduction (64 lanes on CDNA).
    #pragma unroll
    for (int off = 32; off > 0; off >>= 1) {
        s += __shfl_down(s, off, 64);
    }

    // Block-level: 256 threads = 4 waves.
    __shared__ float wave_sums[4];
    int lane = threadIdx.x & 63;
    int wave = threadIdx.x >> 6;
    if (lane == 0) wave_sums[wave] = s;
    __syncthreads();

    if (threadIdx.x == 0) {
        float t = wave_sums[0] + wave_sums[1] + wave_sums[2] + wave_sums[3];
        atomicAdd(out, t);  // device-scope by default on CDNA
    }
}

extern "C" void kernel_launch(void* const* d_in, const int* in_sizes, int n_in,
                              void* d_out, int out_size, void* d_ws, size_t ws_size,
                              hipStream_t stream) {
    const float* items = (const float*)d_in[0];
    float* out = (float*)d_out;
    int n = in_sizes[0];          // 33554432
    int n4 = n / 4;               // 8388608 float4 loads (N is a multiple of 4)

    // d_out is re-poisoned to 0xAA before every call -> must zero it ourselves.
    zero_out_kernel<<<1, 1, 0, stream>>>(out);

    // 4096 blocks x 256 threads = 1M threads, 8 float4 (128 B) per thread.
    masked_sum_kernel<<<4096, 256, 0, stream>>>(items, out, n4);
}

// Round 2
// 204.076 us; speedup vs baseline: 1.0405x; 1.0405x over previous
//
#include <hip/hip_runtime.h>

// Masked sum reduction: s = sum(items[i] for items[i] % 2 == 0), N = 2^25 fp32.
// Memory-bound: 128 MB read -> ~21 us floor at 6.3 TB/s achievable.
//
// Structure: one memset node (zero d_out) + one reduction kernel.
// Each block owns a contiguous tile of BLOCK*8 float4 (32 KB); each thread
// issues 8 independent float4 loads (128 B in flight) before any accumulation,
// mirroring the float4-copy pattern that reaches 6.29 TB/s on MI355X.

constexpr int BLOCK = 256;
constexpr int VPT   = 8;                 // float4 per thread
constexpr int TILE4 = BLOCK * VPT;       // float4 per block tile (2048)

__global__ __launch_bounds__(BLOCK) void masked_sum_kernel(
        const float4* __restrict__ in4, const float* __restrict__ in,
        float* __restrict__ out, int n4, int n, int full_tiles) {
    float s = 0.0f;

    // Full tiles: grid-stride over block-sized contiguous tiles.
    for (int tile = blockIdx.x; tile < full_tiles; tile += gridDim.x) {
        int base = tile * TILE4 + threadIdx.x;
        float4 v[VPT];
        #pragma unroll
        for (int j = 0; j < VPT; ++j)       // 8 independent 16B loads
            v[j] = in4[base + j * BLOCK];
        #pragma unroll
        for (int j = 0; j < VPT; ++j) {
            // integer-valued floats < 2^24: int cast is exact, &1 is the parity
            s += ((((int)v[j].x) & 1) == 0) ? v[j].x : 0.0f;
            s += ((((int)v[j].y) & 1) == 0) ? v[j].y : 0.0f;
            s += ((((int)v[j].z) & 1) == 0) ? v[j].z : 0.0f;
            s += ((((int)v[j].w) & 1) == 0) ? v[j].w : 0.0f;
        }
    }

    // float4 tail beyond the full tiles (none when n4 % TILE4 == 0).
    int gtid = blockIdx.x * BLOCK + threadIdx.x;
    int nthreads = gridDim.x * BLOCK;
    for (int i = full_tiles * TILE4 + gtid; i < n4; i += nthreads) {
        float4 v = in4[i];
        s += ((((int)v.x) & 1) == 0) ? v.x : 0.0f;
        s += ((((int)v.y) & 1) == 0) ? v.y : 0.0f;
        s += ((((int)v.z) & 1) == 0) ? v.z : 0.0f;
        s += ((((int)v.w) & 1) == 0) ? v.w : 0.0f;
    }
    // scalar tail when n % 4 != 0 (none for N = 2^25).
    for (int i = n4 * 4 + gtid; i < n; i += nthreads) {
        float v = in[i];
        s += ((((int)v) & 1) == 0) ? v : 0.0f;
    }

    // Wave-level reduction (64 lanes).
    #pragma unroll
    for (int off = 32; off > 0; off >>= 1)
        s += __shfl_down(s, off, 64);

    // Block-level: 4 waves -> LDS -> one atomic per block.
    __shared__ float wave_sums[BLOCK / 64];
    int lane = threadIdx.x & 63;
    int wave = threadIdx.x >> 6;
    if (lane == 0) wave_sums[wave] = s;
    __syncthreads();
    if (threadIdx.x == 0) {
        float t = wave_sums[0] + wave_sums[1] + wave_sums[2] + wave_sums[3];
        atomicAdd(out, t);   // device-scope by default; 4096 atomics total
    }
}

extern "C" void kernel_launch(void* const* d_in, const int* in_sizes, int n_in,
                              void* d_out, int out_size, void* d_ws, size_t ws_size,
                              hipStream_t stream) {
    const float* items = (const float*)d_in[0];
    float* out = (float*)d_out;
    int n = in_sizes[0];                 // 33554432
    int n4 = n / 4;                      // 8388608 float4
    int full_tiles = n4 / TILE4;         // 4096 for N = 2^25

    // d_out is re-poisoned to 0xAA before every call -> zero via memset node
    // (cheaper than a 1-thread kernel launch; graph-capture safe).
    hipMemsetAsync(out, 0, (size_t)out_size * sizeof(float), stream);

    int grid = full_tiles > 0 ? full_tiles : 1;
    if (grid > 8192) grid = 8192;        // grid-stride covers the rest
    masked_sum_kernel<<<grid, BLOCK, 0, stream>>>(
        (const float4*)items, items, out, n4, n, full_tiles);
}

// Round 3
// 186.599 us; speedup vs baseline: 1.1380x; 1.0937x over previous
//
#include <hip/hip_runtime.h>

// Masked sum reduction: s = sum(items[i] for items[i] % 2 == 0), N = 2^25 fp32.
// Memory-bound: 128 MB read -> ~21 us floor at 6.3 TB/s achievable.
//
// Two-kernel scheme (no same-address atomics, no memset node):
//   k1: 2048 blocks stream the input (32 KB tiles, 8 independent float4/thread),
//       one fp32 partial per block -> d_ws (every slot written, no init needed).
//   k2: single block reduces the 2048 partials and writes out[0].
// Rationale: rounds 1-2 funneled 4096 same-address fp32 atomicAdds into out[0];
// same-address RMWs serialize at one TCC channel and can cost tens of us.

constexpr int BLOCK  = 256;
constexpr int VPT    = 8;                  // float4 per thread per tile
constexpr int TILE4  = BLOCK * VPT;        // 2048 float4 = 32 KB per tile
constexpr int GRID1  = 2048;               // partial count

__global__ __launch_bounds__(BLOCK) void masked_partial_kernel(
        const float4* __restrict__ in4, const float* __restrict__ in,
        float* __restrict__ partials, int n4, int n, int full_tiles) {
    float s = 0.0f;

    // Grid-stride over contiguous 32 KB tiles; 8 independent 16B loads/thread.
    for (int tile = blockIdx.x; tile < full_tiles; tile += gridDim.x) {
        int base = tile * TILE4 + threadIdx.x;
        float4 v[VPT];
        #pragma unroll
        for (int j = 0; j < VPT; ++j)
            v[j] = in4[base + j * BLOCK];
        #pragma unroll
        for (int j = 0; j < VPT; ++j) {
            // integer-valued floats < 2^24: int cast exact, &1 is the parity
            s += ((((int)v[j].x) & 1) == 0) ? v[j].x : 0.0f;
            s += ((((int)v[j].y) & 1) == 0) ? v[j].y : 0.0f;
            s += ((((int)v[j].z) & 1) == 0) ? v[j].z : 0.0f;
            s += ((((int)v[j].w) & 1) == 0) ? v[j].w : 0.0f;
        }
    }

    // Tails (empty for N = 2^25, kept for generality).
    int gtid = blockIdx.x * BLOCK + threadIdx.x;
    int nthreads = gridDim.x * BLOCK;
    for (int i = full_tiles * TILE4 + gtid; i < n4; i += nthreads) {
        float4 v = in4[i];
        s += ((((int)v.x) & 1) == 0) ? v.x : 0.0f;
        s += ((((int)v.y) & 1) == 0) ? v.y : 0.0f;
        s += ((((int)v.z) & 1) == 0) ? v.z : 0.0f;
        s += ((((int)v.w) & 1) == 0) ? v.w : 0.0f;
    }
    for (int i = n4 * 4 + gtid; i < n; i += nthreads) {
        float v = in[i];
        s += ((((int)v) & 1) == 0) ? v : 0.0f;
    }

    // Wave reduce (64 lanes), then 4 waves -> LDS -> one store per block.
    #pragma unroll
    for (int off = 32; off > 0; off >>= 1)
        s += __shfl_down(s, off, 64);

    __shared__ float wave_sums[BLOCK / 64];
    int lane = threadIdx.x & 63;
    int wave = threadIdx.x >> 6;
    if (lane == 0) wave_sums[wave] = s;
    __syncthreads();
    if (threadIdx.x == 0)
        partials[blockIdx.x] = wave_sums[0] + wave_sums[1] +
                               wave_sums[2] + wave_sums[3];
}

__global__ __launch_bounds__(BLOCK) void final_reduce_kernel(
        const float* __restrict__ partials, float* __restrict__ out, int p) {
    float s = 0.0f;
    for (int i = threadIdx.x; i < p; i += BLOCK)
        s += partials[i];

    #pragma unroll
    for (int off = 32; off > 0; off >>= 1)
        s += __shfl_down(s, off, 64);

    __shared__ float wave_sums[BLOCK / 64];
    int lane = threadIdx.x & 63;
    int wave = threadIdx.x >> 6;
    if (lane == 0) wave_sums[wave] = s;
    __syncthreads();
    if (threadIdx.x == 0)
        out[0] = wave_sums[0] + wave_sums[1] + wave_sums[2] + wave_sums[3];
}

extern "C" void kernel_launch(void* const* d_in, const int* in_sizes, int n_in,
                              void* d_out, int out_size, void* d_ws, size_t ws_size,
                              hipStream_t stream) {
    const float* items = (const float*)d_in[0];
    float* out = (float*)d_out;
    float* partials = (float*)d_ws;      // GRID1 floats, all written by k1
    int n = in_sizes[0];                 // 33554432
    int n4 = n / 4;                      // 8388608 float4
    int full_tiles = n4 / TILE4;         // 4096

    masked_partial_kernel<<<GRID1, BLOCK, 0, stream>>>(
        (const float4*)items, items, partials, n4, n, full_tiles);
    final_reduce_kernel<<<1, BLOCK, 0, stream>>>(partials, out, GRID1);
}